// Round 1
// 809.832 us; speedup vs baseline: 1.1227x; 1.1227x over previous
//
#include <hip/hip_runtime.h>
#include <hip/hip_bf16.h>
#include <math.h>

typedef __hip_bfloat16 bf16_t;
typedef __attribute__((ext_vector_type(8))) short short8;
typedef __attribute__((ext_vector_type(4))) float f32x4;

#define S_LEN 1024
#define HID   4096
#define NH    32
#define HD    128
#define KB_N  2048
#define TOPK  100
#define SCALE 0.08838834764831845f   // 1/sqrt(128)

typedef const __attribute__((address_space(1))) void* gptr_t;
typedef __attribute__((address_space(3))) void* lptr_t;

#define VM8 asm volatile("s_waitcnt vmcnt(8)" ::: "memory")
#define VM4 asm volatile("s_waitcnt vmcnt(4)" ::: "memory")
#define VM0 asm volatile("s_waitcnt vmcnt(0)" ::: "memory")

// ============================================================
// K0: zero d_out (for split-K atomics) and hssum (for colsum atomics)
// ============================================================
__global__ void k0_zero(float* __restrict__ out, float* __restrict__ hssum) {
  int tid = threadIdx.x;
  if (blockIdx.x < 4096) {
    float4 z = {0.f, 0.f, 0.f, 0.f};
    *(float4*)(out + ((size_t)blockIdx.x * 256 + tid) * 4) = z;
  } else {
    float4 z = {0.f, 0.f, 0.f, 0.f};
    *(float4*)(hssum + tid * 4) = z;
    *(float4*)(hssum + 1024 + tid * 4) = z;
    *(float4*)(hssum + 2048 + tid * 4) = z;
    *(float4*)(hssum + 3072 + tid * 4) = z;
  }
}

// ============================================================
// Kw: convert 5 weight matrices fp32 -> bf16 (Wq,Wq2,Wk,Wv -> Wcat; Wo -> Wob)
// ============================================================
__global__ void kw_conv(const float* __restrict__ Wq, const float* __restrict__ Wq2,
                        const float* __restrict__ Wk, const float* __restrict__ Wv,
                        const float* __restrict__ Wo,
                        bf16_t* __restrict__ Wcat, bf16_t* __restrict__ Wob) {
  int w = blockIdx.y;
  const float* src = (w == 0) ? Wq : (w == 1) ? Wq2 : (w == 2) ? Wk : (w == 3) ? Wv : Wo;
  bf16_t* dst = (w < 4) ? (Wcat + (size_t)w * 16777216) : Wob;
  size_t i = ((size_t)blockIdx.x * 256 + threadIdx.x) * 4;
  float4 f = *(const float4*)(src + i);
  union { bf16_t h[4]; uint2 u; } p;
  p.h[0] = __float2bfloat16(f.x); p.h[1] = __float2bfloat16(f.y);
  p.h[2] = __float2bfloat16(f.z); p.h[3] = __float2bfloat16(f.w);
  *(uint2*)(dst + i) = p.u;
}

// ============================================================
// K1a: hidden fp32 -> bf16 (massively parallel)
// ============================================================
__global__ void k1_convert(const float* __restrict__ hs, bf16_t* __restrict__ hsb) {
  size_t i = ((size_t)blockIdx.x * 256 + threadIdx.x) * 4;
  float4 f = *(const float4*)(hs + i);
  union { bf16_t h[4]; uint2 u; } p;
  p.h[0] = __float2bfloat16(f.x); p.h[1] = __float2bfloat16(f.y);
  p.h[2] = __float2bfloat16(f.z); p.h[3] = __float2bfloat16(f.w);
  *(uint2*)(hsb + i) = p.u;
}

// ============================================================
// K1b: column sums of hs (fp32), 256 blocks, atomic partials
// ============================================================
__global__ void k1_colsum(const float* __restrict__ hs, float* __restrict__ hssum) {
  int col = blockIdx.x * 256 + threadIdx.x;   // blockIdx.x 0..15
  int r0 = blockIdx.y * 64;                   // blockIdx.y 0..15
  float acc = 0.f;
#pragma unroll 8
  for (int r = 0; r < 64; r++) acc += hs[(size_t)(r0 + r) * HID + col];
  atomicAdd(hssum + col, acc);
}

// ============================================================
// K2: q2sum[i] = sum_k hssum[k] * Wq2[i,k]   (fp32, 1 wave/row)
// ============================================================
__global__ void k2_q2sum(const float* __restrict__ W,
                         const float* __restrict__ hssum,
                         float* __restrict__ q2sum) {
  int wave = threadIdx.x >> 6, lane = threadIdx.x & 63;
  int row = blockIdx.x * 4 + wave;
  const float4* wr = (const float4*)(W + (size_t)row * HID);
  const float4* xr = (const float4*)hssum;
  float acc = 0.f;
#pragma unroll
  for (int it = 0; it < 16; it++) {
    float4 a = wr[it * 64 + lane];
    float4 b = xr[it * 64 + lane];
    acc += a.x * b.x + a.y * b.y + a.z * b.z + a.w * b.w;
  }
#pragma unroll
  for (int off = 32; off > 0; off >>= 1) acc += __shfl_xor(acc, off, 64);
  if (lane == 0) q2sum[row] = acc;
}

// ============================================================
// K3: kb_scores[kb] = scale * dot(q2sum, kb_keys[kb, 0:4096])
// ============================================================
__global__ void k3_kbscore(const float* __restrict__ kbk,
                           const float* __restrict__ q2sum,
                           float* __restrict__ scores) {
  int wave = threadIdx.x >> 6, lane = threadIdx.x & 63;
  int row = blockIdx.x * 4 + wave;
  const float4* kr = (const float4*)(kbk + (size_t)row * 8192);  // slot 0 of 2
  const float4* xr = (const float4*)q2sum;
  float acc = 0.f;
#pragma unroll
  for (int it = 0; it < 16; it++) {
    float4 a = kr[it * 64 + lane];
    float4 b = xr[it * 64 + lane];
    acc += a.x * b.x + a.y * b.y + a.z * b.z + a.w * b.w;
  }
#pragma unroll
  for (int off = 32; off > 0; off >>= 1) acc += __shfl_xor(acc, off, 64);
  if (lane == 0) scores[row] = acc * SCALE;
}

// ============================================================
// K4: top-100 of 2048 scores, single wave, iterative argmax.
// ============================================================
__global__ void k4_topk(const float* __restrict__ scores, int* __restrict__ tidx) {
  int lane = threadIdx.x;  // blockDim = 64
  float v[32];
#pragma unroll
  for (int i = 0; i < 32; i++) v[i] = scores[i * 64 + lane];
  for (int t = 0; t < TOPK; t++) {
    float bm = -INFINITY; int bi = 0x7fffffff;
#pragma unroll
    for (int i = 0; i < 32; i++) {
      if (v[i] > bm) { bm = v[i]; bi = i * 64 + lane; }
    }
#pragma unroll
    for (int off = 32; off > 0; off >>= 1) {
      float ov = __shfl_xor(bm, off, 64);
      int   oi = __shfl_xor(bi, off, 64);
      if (ov > bm || (ov == bm && oi < bi)) { bm = ov; bi = oi; }
    }
    if (lane == 0) tidx[t] = bi;
    if ((bi & 63) == lane) {
      int slot = bi >> 6;
#pragma unroll
      for (int i = 0; i < 32; i++) if (i == slot) v[i] = -INFINITY;
    }
  }
}

// ============================================================
// K5: gather top-k KB rows (slot 0) -> bf16 [128][4096], zero-pad rows 100..127
// ============================================================
__global__ void k5_gather(const float* __restrict__ kbk, const float* __restrict__ kbv,
                          const int* __restrict__ tidx,
                          bf16_t* __restrict__ kbkt, bf16_t* __restrict__ kbvt) {
  int j = blockIdx.x;            // 0..127
  int tid = threadIdx.x;         // 256
  if (j < TOPK) {
    size_t src = (size_t)tidx[j] * 8192;
#pragma unroll
    for (int r = 0; r < 4; r++) {
      int i = (tid + r * 256) * 4;
      float4 a = *(const float4*)(kbk + src + i);
      float4 b = *(const float4*)(kbv + src + i);
      union { bf16_t h[4]; uint2 u; } pa, pb;
      pa.h[0] = __float2bfloat16(a.x); pa.h[1] = __float2bfloat16(a.y);
      pa.h[2] = __float2bfloat16(a.z); pa.h[3] = __float2bfloat16(a.w);
      pb.h[0] = __float2bfloat16(b.x); pb.h[1] = __float2bfloat16(b.y);
      pb.h[2] = __float2bfloat16(b.z); pb.h[3] = __float2bfloat16(b.w);
      *(uint2*)(kbkt + (size_t)j * HID + i) = pa.u;
      *(uint2*)(kbvt + (size_t)j * HID + i) = pb.u;
    }
  } else {
    uint2 z; z.x = 0u; z.y = 0u;
#pragma unroll
    for (int r = 0; r < 4; r++) {
      int i = (tid + r * 256) * 4;
      *(uint2*)(kbkt + (size_t)j * HID + i) = z;
      *(uint2*)(kbvt + (size_t)j * HID + i) = z;
    }
  }
}

// ============================================================
// gemm_256: C = A[1024,K]*B[N,K]^T, bf16 in, 256x256 tile, BK=32,
// 8 waves (2x4), ring of 4 LDS K-tile buffers (128 KiB total),
// global_load_lds staged 3 tiles ahead, counted vmcnt(8) boundaries
// (never drains in steady state), chunk-XOR LDS swizzle (conflict-free
// ds_read_b128), setprio around the two 16-MFMA clusters.
//   Ring safety proof: tile t+3 writes buf[(t+3)&3] == buf[(t-1)&3],
//   whose last reads (tile t-1) completed before the boundary barrier
//   this wave passed before issuing the stage.
// MODE 0: proj  — N=16384 (Wcat), bf16 out to 4 buffers by bn>>12.
// MODE 1: wo    — N=4096, split-K by blockIdx.z (4 x 1024), fp32 atomicAdd.
// ============================================================
template<int MODE>
__global__ __launch_bounds__(512, 2) void gemm_256(
    const bf16_t* __restrict__ A, const bf16_t* __restrict__ B,
    void* O0, void* O1, void* O2, void* O3) {
  __shared__ __attribute__((aligned(16))) bf16_t sm[4 * 16384];  // 128 KiB
  const int tid  = threadIdx.x;
  const int wave = tid >> 6, lane = tid & 63;
  const int lrow = lane & 15, quad = lane >> 4;
  const int wr = wave >> 2, wc = wave & 3;        // 2 x 4 wave grid
  const int bm = blockIdx.y * 256;
  const int bn = blockIdx.x * 256;
  // staging coords: thread stages physical 16B chunk (tid&3) of row srow
  // (and srow+128); logical chunk = physical ^ ((row>>1)&3)  [involution]
  const int srow = tid >> 2;                       // 0..127
  const int lc   = (tid & 3) ^ ((srow >> 1) & 3);  // pre-swizzled global chunk
  const int pc   = quad ^ ((lrow >> 1) & 3);       // swizzled read chunk (const/lane)

  const int kbeg = (MODE == 1) ? blockIdx.z * 1024 : 0;
  const int NT   = (MODE == 1) ? 32 : 128;

  const bf16_t* aS = A + (size_t)(bm + srow) * 4096 + kbeg + lc * 8;
  const bf16_t* bS = B + (size_t)(bn + srow) * 4096 + kbeg + lc * 8;
  bf16_t* const lw = sm + wave * 512;              // wave-uniform LDS base

  f32x4 acc[8][4];
  const f32x4 zero4 = {0.f, 0.f, 0.f, 0.f};
#pragma unroll
  for (int i = 0; i < 8; i++)
#pragma unroll
    for (int j = 0; j < 4; j++) acc[i][j] = zero4;

  auto STAGE = [&](int tt) {
    bf16_t* l = lw + (tt & 3) * 16384;
    const bf16_t* ga = aS + tt * 32;
    const bf16_t* gb = bS + tt * 32;
    __builtin_amdgcn_global_load_lds((gptr_t)ga,             (lptr_t)l,           16, 0, 0);
    __builtin_amdgcn_global_load_lds((gptr_t)(ga + 524288),  (lptr_t)(l + 4096),  16, 0, 0);
    __builtin_amdgcn_global_load_lds((gptr_t)gb,             (lptr_t)(l + 8192),  16, 0, 0);
    __builtin_amdgcn_global_load_lds((gptr_t)(gb + 524288),  (lptr_t)(l + 12288), 16, 0, 0);
  };

  // prologue: prime 3 tiles (12 loads/wave), wait for tile 0 (oldest 4)
  STAGE(0); STAGE(1); STAGE(2);
  VM8;
  __builtin_amdgcn_s_barrier();

  auto body = [&](int t, bool do_stage) {
    const bf16_t* Ab = sm + (t & 3) * 16384 + (wr * 128 + lrow) * 32 + pc * 8;
    const bf16_t* Bb = sm + (t & 3) * 16384 + 8192 + (wc * 64 + lrow) * 32 + pc * 8;
    if (do_stage) STAGE(t + 3);
    short8 af[4], bfr[4];
#pragma unroll
    for (int j = 0; j < 4; j++) bfr[j] = *(const short8*)(Bb + j * 512);
#pragma unroll
    for (int i = 0; i < 4; i++) af[i] = *(const short8*)(Ab + i * 512);
    __builtin_amdgcn_s_setprio(1);
#pragma unroll
    for (int i = 0; i < 4; i++)
#pragma unroll
      for (int j = 0; j < 4; j++)
        acc[i][j] = __builtin_amdgcn_mfma_f32_16x16x32_bf16(af[i], bfr[j], acc[i][j], 0, 0, 0);
    __builtin_amdgcn_s_setprio(0);
#pragma unroll
    for (int i = 0; i < 4; i++) af[i] = *(const short8*)(Ab + (i + 4) * 512);
    __builtin_amdgcn_s_setprio(1);
#pragma unroll
    for (int i = 0; i < 4; i++)
#pragma unroll
      for (int j = 0; j < 4; j++)
        acc[i + 4][j] = __builtin_amdgcn_mfma_f32_16x16x32_bf16(af[i], bfr[j], acc[i + 4][j], 0, 0, 0);
    __builtin_amdgcn_s_setprio(0);
  };

  // steady state: 12 loads in flight at boundary; vmcnt(8) -> next tile landed
  for (int t = 0; t < NT - 3; ++t) {
    body(t, true);
    VM8;
    __builtin_amdgcn_s_barrier();
  }
  body(NT - 3, false); VM4; __builtin_amdgcn_s_barrier();
  body(NT - 2, false); VM0; __builtin_amdgcn_s_barrier();
  body(NT - 1, false);

  if (MODE == 0) {
    bf16_t* dst = (bf16_t*)((bn >> 12) == 0 ? O0 : (bn >> 12) == 1 ? O1
                          : (bn >> 12) == 2 ? O2 : O3);
    const int nb = bn & 4095;
#pragma unroll
    for (int i = 0; i < 8; i++)
#pragma unroll
      for (int j = 0; j < 4; j++)
#pragma unroll
        for (int r = 0; r < 4; r++) {
          int m = bm + wr * 128 + i * 16 + quad * 4 + r;
          int n = nb + wc * 64 + j * 16 + lrow;
          dst[(size_t)m * 4096 + n] = __float2bfloat16(acc[i][j][r]);
        }
  } else {
    float* dst = (float*)O0;
#pragma unroll
    for (int i = 0; i < 8; i++)
#pragma unroll
      for (int j = 0; j < 4; j++)
#pragma unroll
        for (int r = 0; r < 4; r++) {
          int m = bm + wr * 128 + i * 16 + quad * 4 + r;
          int n = bn + wc * 64 + j * 16 + lrow;
          atomicAdd(dst + (size_t)m * 4096 + n, acc[i][j][r]);
        }
  }
}

// ============================================================
// Fallback GEMM (round-1 structure) used when ws is too small for bf16 weights
// ============================================================
template<int OUT_BF16>
__global__ __launch_bounds__(256) void gemm_bt(
    const bf16_t* __restrict__ A,
    const float* __restrict__ B0, const float* __restrict__ B1,
    const float* __restrict__ B2, const float* __restrict__ B3,
    void* C0, void* C1, void* C2, void* C3) {
  const int z = blockIdx.z;
  const float* __restrict__ B = (z == 0) ? B0 : (z == 1) ? B1 : (z == 2) ? B2 : B3;
  void* Cv = (z == 0) ? C0 : (z == 1) ? C1 : (z == 2) ? C2 : C3;
  __shared__ bf16_t As[128][40];
  __shared__ bf16_t Bs[128][40];
  const int tid = threadIdx.x;
  const int bm = blockIdx.y * 128, bn = blockIdx.x * 128;
  const int wave = tid >> 6, lane = tid & 63;
  const int wr = wave >> 1, wc = wave & 1;
  const int lrow = lane & 15, quad = lane >> 4;
  f32x4 acc[4][4];
  const f32x4 zero4 = {0.f, 0.f, 0.f, 0.f};
#pragma unroll
  for (int i = 0; i < 4; i++)
#pragma unroll
    for (int j = 0; j < 4; j++) acc[i][j] = zero4;
  const int arow = tid >> 2, ach = tid & 3;
  const int brow = tid >> 3, bch = tid & 7;
  for (int k0 = 0; k0 < 4096; k0 += 32) {
    __syncthreads();
#pragma unroll
    for (int r = 0; r < 2; r++) {
      int row = arow + r * 64;
      uint4 val = *(const uint4*)(A + (size_t)(bm + row) * 4096 + k0 + ach * 8);
      *(uint4*)(&As[row][ach * 8]) = val;
    }
#pragma unroll
    for (int r = 0; r < 4; r++) {
      int row = brow + r * 32;
      float4 f = *(const float4*)(B + (size_t)(bn + row) * 4096 + k0 + bch * 4);
      union { bf16_t h[4]; uint2 u; } p;
      p.h[0] = __float2bfloat16(f.x); p.h[1] = __float2bfloat16(f.y);
      p.h[2] = __float2bfloat16(f.z); p.h[3] = __float2bfloat16(f.w);
      *(uint2*)(&Bs[row][bch * 4]) = p.u;
    }
    __syncthreads();
    short8 af[4], bfr[4];
#pragma unroll
    for (int i = 0; i < 4; i++)
      af[i] = *(const short8*)(&As[wr * 64 + i * 16 + lrow][quad * 8]);
#pragma unroll
    for (int j = 0; j < 4; j++)
      bfr[j] = *(const short8*)(&Bs[wc * 64 + j * 16 + lrow][quad * 8]);
#pragma unroll
    for (int i = 0; i < 4; i++)
#pragma unroll
      for (int j = 0; j < 4; j++)
        acc[i][j] = __builtin_amdgcn_mfma_f32_16x16x32_bf16(af[i], bfr[j], acc[i][j], 0, 0, 0);
  }
#pragma unroll
  for (int i = 0; i < 4; i++)
#pragma unroll
    for (int j = 0; j < 4; j++)
#pragma unroll
      for (int r = 0; r < 4; r++) {
        int m = bm + wr * 64 + i * 16 + quad * 4 + r;
        int n = bn + wc * 64 + j * 16 + lrow;
        if (OUT_BF16)
          ((bf16_t*)Cv)[(size_t)m * 4096 + n] = __float2bfloat16(acc[i][j][r]);
        else
          ((float*)Cv)[(size_t)m * 4096 + n] = acc[i][j][r];
      }
}

// ============================================================
// K7: RoPE on q and k (bf16 in-place). pair (d, d+64), d<64.
// ============================================================
__global__ void k7_rope(bf16_t* __restrict__ q, bf16_t* __restrict__ k,
                        const int* __restrict__ pos_ids) {
  int t = blockIdx.x * 256 + threadIdx.x;
  int d = t & 63;
  int h = (t >> 6) & 31;
  int s = t >> 11;
  float pos = (float)pos_ids[s];
  float inv = exp2f(-(float)d * 0.20762050593046f);
  float ang = pos * inv;
  float c = cosf(ang), si = sinf(ang);
  size_t i1 = (size_t)s * HID + h * HD + d;
  size_t i2 = i1 + 64;
  float a1 = __bfloat162float(q[i1]), a2 = __bfloat162float(q[i2]);
  q[i1] = __float2bfloat16(a1 * c - a2 * si);
  q[i2] = __float2bfloat16(a2 * c + a1 * si);
  float b1 = __bfloat162float(k[i1]), b2 = __bfloat162float(k[i2]);
  k[i1] = __float2bfloat16(b1 * c - b2 * si);
  k[i2] = __float2bfloat16(b2 * c + b1 * si);
}

// ============================================================
// K8: flash attention (unchanged)
// ============================================================
#define FA_PAD 136
__global__ __launch_bounds__(256) void k8_flash(
    const bf16_t* __restrict__ qg, const bf16_t* __restrict__ q2g,
    const bf16_t* __restrict__ kg, const bf16_t* __restrict__ vg,
    const bf16_t* __restrict__ kbkt, const bf16_t* __restrict__ kbvt,
    const float* __restrict__ shift_p,
    bf16_t* __restrict__ outb) {
  __shared__ bf16_t KV[128][FA_PAD];
  __shared__ bf16_t Ps[4][16][FA_PAD];
  int qt = 15 - (int)blockIdx.x;
  int h = blockIdx.y;
  int q0 = qt * 64;
  int tid = threadIdx.x;
  int wave = tid >> 6, lane = tid & 63;
  int lrow = lane & 15, quad = lane >> 4;

  short8 qf[4], q2f[4];
  {
    const size_t base = (size_t)(q0 + wave * 16 + lrow) * HID + h * HD;
#pragma unroll
    for (int kc = 0; kc < 4; kc++) {
      qf[kc]  = *(const short8*)(qg  + base + kc * 32 + quad * 8);
      q2f[kc] = *(const short8*)(q2g + base + kc * 32 + quad * 8);
    }
  }
  const f32x4 zero4 = {0.f, 0.f, 0.f, 0.f};
  f32x4 O[8];
#pragma unroll
  for (int df = 0; df < 8; df++) O[df] = zero4;
  float m_i[4], l_i[4];
#pragma unroll
  for (int r = 0; r < 4; r++) { m_i[r] = -INFINITY; l_i[r] = 0.f; }
  float shift = shift_p[h];

  int nt = (q0 + 63) / 128 + 1;
  for (int tile = -1; tile < nt; tile++) {
    const bf16_t* ksrc = (tile < 0) ? (kbkt + h * HD)
                                    : (kg + (size_t)tile * 128 * HID + h * HD);
    const bf16_t* vsrc = (tile < 0) ? (kbvt + h * HD)
                                    : (vg + (size_t)tile * 128 * HID + h * HD);
    __syncthreads();
    {
      int rbase = tid >> 4, ch = tid & 15;
#pragma unroll
      for (int rr = 0; rr < 8; rr++) {
        int row = rr * 16 + rbase;
        uint4 val = *(const uint4*)(ksrc + (size_t)row * HID + ch * 8);
        *(uint4*)(&KV[row][ch * 8]) = val;
      }
    }
    __syncthreads();
    f32x4 Sv[8];
#pragma unroll
    for (int jf = 0; jf < 8; jf++) {
      short8 kf[4];
#pragma unroll
      for (int kc = 0; kc < 4; kc++)
        kf[kc] = *(const short8*)(&KV[jf * 16 + lrow][kc * 32 + quad * 8]);
      f32x4 s = zero4;
      if (tile < 0) {
#pragma unroll
        for (int kc = 0; kc < 4; kc++)
          s = __builtin_amdgcn_mfma_f32_16x16x32_bf16(q2f[kc], kf[kc], s, 0, 0, 0);
      } else {
#pragma unroll
        for (int kc = 0; kc < 4; kc++)
          s = __builtin_amdgcn_mfma_f32_16x16x32_bf16(qf[kc], kf[kc], s, 0, 0, 0);
      }
      Sv[jf] = s;
    }
#pragma unroll
    for (int jf = 0; jf < 8; jf++)
#pragma unroll
      for (int r = 0; r < 4; r++) {
        float val = Sv[jf][r] * SCALE;
        if (tile < 0) {
          val += shift;
          int col = jf * 16 + lrow;
          if (col >= TOPK) val = -1e30f;
        } else {
          int srow = q0 + wave * 16 + quad * 4 + r;
          int tcol = tile * 128 + jf * 16 + lrow;
          if (tcol > srow) val -= 1e9f;
        }
        Sv[jf][r] = val;
      }
    float alpha[4];
#pragma unroll
    for (int r = 0; r < 4; r++) {
      float tm = Sv[0][r];
#pragma unroll
      for (int jf = 1; jf < 8; jf++) tm = fmaxf(tm, Sv[jf][r]);
#pragma unroll
      for (int off = 1; off < 16; off <<= 1) tm = fmaxf(tm, __shfl_xor(tm, off, 64));
      float mn = fmaxf(m_i[r], tm);
      alpha[r] = __expf(m_i[r] - mn);
      m_i[r] = mn;
    }
    float rsum[4] = {0.f, 0.f, 0.f, 0.f};
#pragma unroll
    for (int jf = 0; jf < 8; jf++)
#pragma unroll
      for (int r = 0; r < 4; r++) {
        float p = __expf(Sv[jf][r] - m_i[r]);
        Sv[jf][r] = p;
        rsum[r] += p;
      }
#pragma unroll
    for (int r = 0; r < 4; r++) {
#pragma unroll
      for (int off = 1; off < 16; off <<= 1) rsum[r] += __shfl_xor(rsum[r], off, 64);
      l_i[r] = l_i[r] * alpha[r] + rsum[r];
    }
#pragma unroll
    for (int jf = 0; jf < 8; jf++)
#pragma unroll
      for (int r = 0; r < 4; r++)
        Ps[wave][quad * 4 + r][jf * 16 + lrow] = __float2bfloat16(Sv[jf][r]);
#pragma unroll
    for (int df = 0; df < 8; df++)
#pragma unroll
      for (int r = 0; r < 4; r++) O[df][r] *= alpha[r];
    __syncthreads();
    {
      int rbase = tid >> 4, ch = tid & 15;
#pragma unroll
      for (int rr = 0; rr < 8; rr++) {
        int t = rr * 16 + rbase;
        union { uint4 u; bf16_t hx[8]; } vv;
        vv.u = *(const uint4*)(vsrc + (size_t)t * HID + ch * 8);
        int cs = ((t >> 3) ^ ch) & 15;
        int tl = t & 7;
#pragma unroll
        for (int e = 0; e < 8; e++)
          KV[ch * 8 + e][cs * 8 + tl] = vv.hx[e];
      }
    }
    __syncthreads();
    short8 pf[4];
#pragma unroll
    for (int kc = 0; kc < 4; kc++)
      pf[kc] = *(const short8*)(&Ps[wave][lrow][kc * 32 + quad * 8]);
#pragma unroll
    for (int df = 0; df < 8; df++) {
      int d = df * 16 + lrow;
      int sw = (d >> 3) & 15;
#pragma unroll
      for (int kc = 0; kc < 4; kc++) {
        short8 vf = *(const short8*)(&KV[d][(((kc * 4 + quad) ^ sw) & 15) * 8]);
        O[df] = __builtin_amdgcn_mfma_f32_16x16x32_bf16(pf[kc], vf, O[df], 0, 0, 0);
      }
    }
  }
#pragma unroll
  for (int df = 0; df < 8; df++)
#pragma unroll
    for (int r = 0; r < 4; r++) {
      int srow = q0 + wave * 16 + quad * 4 + r;
      float val = O[df][r] / l_i[r];
      outb[(size_t)srow * HID + h * HD + df * 16 + lrow] = __float2bfloat16(val);
    }
}

// ============================================================
extern "C" void kernel_launch(void* const* d_in, const int* in_sizes, int n_in,
                              void* d_out, int out_size, void* d_ws, size_t ws_size,
                              hipStream_t stream) {
  const float* hs    = (const float*)d_in[0];
  const int*   pos   = (const int*)d_in[2];
  const float* kbk   = (const float*)d_in[3];
  const float* kbv   = (const float*)d_in[4];
  const float* Wq    = (const float*)d_in[5];
  const float* Wq2   = (const float*)d_in[6];
  const float* Wk    = (const float*)d_in[7];
  const float* Wv    = (const float*)d_in[8];
  const float* Wo    = (const float*)d_in[9];
  const float* shift = (const float*)d_in[10];
  float* out = (float*)d_out;

  char* ws = (char*)d_ws;
  const size_t MB8 = 8388608;
  bf16_t* qb    = (bf16_t*)(ws);
  bf16_t* q2b   = (bf16_t*)(ws + MB8);
  bf16_t* kbuf  = (bf16_t*)(ws + 2 * MB8);
  bf16_t* vbuf  = (bf16_t*)(ws + 3 * MB8);
  bf16_t* hsb   = (bf16_t*)(ws + 4 * MB8);   // reused as attn output
  bf16_t* kbkt  = (bf16_t*)(ws + 5 * MB8);
  bf16_t* kbvt  = (bf16_t*)(ws + 5 * MB8 + 1048576);
  float*  hssum = (float*)(ws + 5 * MB8 + 2 * 1048576);
  float*  q2s   = (float*)(ws + 5 * MB8 + 2 * 1048576 + 16384);
  float*  scr   = (float*)(ws + 5 * MB8 + 2 * 1048576 + 32768);
  int*    tidx  = (int*)(ws + 5 * MB8 + 2 * 1048576 + 40960);
  bf16_t* attnb = hsb;
  // bf16 weight staging
  const size_t WCAT_OFF = 48ull * 1048576;
  bf16_t* Wcat = (bf16_t*)(ws + WCAT_OFF);                 // 128 MB
  bf16_t* Wob  = (bf16_t*)(ws + WCAT_OFF + 134217728);     // 32 MB
  const size_t WS_NEED = WCAT_OFF + 134217728 + 33554432;
  const bool big_ws = (ws_size >= WS_NEED);

  k0_zero<<<dim3(4097), dim3(256), 0, stream>>>(out, hssum);
  if (big_ws)
    kw_conv<<<dim3(16384, 5), dim3(256), 0, stream>>>(Wq, Wq2, Wk, Wv, Wo, Wcat, Wob);
  k1_convert<<<dim3(4096), dim3(256), 0, stream>>>(hs, hsb);
  k1_colsum<<<dim3(16, 16), dim3(256), 0, stream>>>(hs, hssum);
  k2_q2sum<<<dim3(1024), dim3(256), 0, stream>>>(Wq2, hssum, q2s);
  k3_kbscore<<<dim3(512), dim3(256), 0, stream>>>(kbk, q2s, scr);
  k4_topk<<<dim3(1), dim3(64), 0, stream>>>(scr, tidx);
  k5_gather<<<dim3(128), dim3(256), 0, stream>>>(kbk, kbv, tidx, kbkt, kbvt);

  if (big_ws) {
    // 256x256 tiles: grid 64x4 = 256 blocks = 1 per CU
    gemm_256<0><<<dim3(64, 4), dim3(512), 0, stream>>>(
        hsb, Wcat, (void*)qb, (void*)q2b, (void*)kbuf, (void*)vbuf);
  } else {
    gemm_bt<1><<<dim3(32, 8, 4), dim3(256), 0, stream>>>(
        hsb, Wq, Wq2, Wk, Wv, (void*)qb, (void*)q2b, (void*)kbuf, (void*)vbuf);
  }
  k7_rope<<<dim3(8192), dim3(256), 0, stream>>>(qb, kbuf, pos);
  k8_flash<<<dim3(16, 32), dim3(256), 0, stream>>>(
      qb, q2b, kbuf, vbuf, kbkt, kbvt, shift, attnb);
  if (big_ws) {
    // split-K=4: grid 16x4x4 = 256 blocks
    gemm_256<1><<<dim3(16, 4, 4), dim3(512), 0, stream>>>(
        attnb, Wob, (void*)out, nullptr, nullptr, nullptr);
  } else {
    gemm_bt<0><<<dim3(32, 8, 1), dim3(256), 0, stream>>>(
        attnb, Wo, Wo, Wo, Wo, (void*)out, (void*)out, (void*)out, (void*)out);
  }
}

// Round 2
// 758.748 us; speedup vs baseline: 1.1983x; 1.0673x over previous
//
#include <hip/hip_runtime.h>
#include <hip/hip_bf16.h>
#include <math.h>

typedef __hip_bfloat16 bf16_t;
typedef __attribute__((ext_vector_type(8))) short short8;
typedef __attribute__((ext_vector_type(4))) float f32x4;

#define S_LEN 1024
#define HID   4096
#define NH    32
#define HD    128
#define KB_N  2048
#define TOPK  100
#define SCALE 0.08838834764831845f   // 1/sqrt(128)

typedef const __attribute__((address_space(1))) void* gptr_t;
typedef __attribute__((address_space(3))) void* lptr_t;

#define VM4 asm volatile("s_waitcnt vmcnt(4)" ::: "memory")
#define VM0 asm volatile("s_waitcnt vmcnt(0)" ::: "memory")

// ============================================================
// K0: zero hssum (for colsum atomics). out no longer needs zeroing
// (Wo GEMM writes every element, no atomics).
// ============================================================
__global__ void k0_zero(float* __restrict__ hssum) {
  int tid = threadIdx.x;
  float4 z = {0.f, 0.f, 0.f, 0.f};
  *(float4*)(hssum + tid * 4) = z;
  *(float4*)(hssum + 1024 + tid * 4) = z;
  *(float4*)(hssum + 2048 + tid * 4) = z;
  *(float4*)(hssum + 3072 + tid * 4) = z;
}

// ============================================================
// Kw: convert 5 weight matrices fp32 -> bf16 (Wq,Wq2,Wk,Wv -> Wcat; Wo -> Wob)
// ============================================================
__global__ void kw_conv(const float* __restrict__ Wq, const float* __restrict__ Wq2,
                        const float* __restrict__ Wk, const float* __restrict__ Wv,
                        const float* __restrict__ Wo,
                        bf16_t* __restrict__ Wcat, bf16_t* __restrict__ Wob) {
  int w = blockIdx.y;
  const float* src = (w == 0) ? Wq : (w == 1) ? Wq2 : (w == 2) ? Wk : (w == 3) ? Wv : Wo;
  bf16_t* dst = (w < 4) ? (Wcat + (size_t)w * 16777216) : Wob;
  size_t i = ((size_t)blockIdx.x * 256 + threadIdx.x) * 4;
  float4 f = *(const float4*)(src + i);
  union { bf16_t h[4]; uint2 u; } p;
  p.h[0] = __float2bfloat16(f.x); p.h[1] = __float2bfloat16(f.y);
  p.h[2] = __float2bfloat16(f.z); p.h[3] = __float2bfloat16(f.w);
  *(uint2*)(dst + i) = p.u;
}

// ============================================================
// K1a: hidden fp32 -> bf16 (massively parallel)
// ============================================================
__global__ void k1_convert(const float* __restrict__ hs, bf16_t* __restrict__ hsb) {
  size_t i = ((size_t)blockIdx.x * 256 + threadIdx.x) * 4;
  float4 f = *(const float4*)(hs + i);
  union { bf16_t h[4]; uint2 u; } p;
  p.h[0] = __float2bfloat16(f.x); p.h[1] = __float2bfloat16(f.y);
  p.h[2] = __float2bfloat16(f.z); p.h[3] = __float2bfloat16(f.w);
  *(uint2*)(hsb + i) = p.u;
}

// ============================================================
// K1b: column sums of hs (fp32), atomic partials
// ============================================================
__global__ void k1_colsum(const float* __restrict__ hs, float* __restrict__ hssum) {
  int col = blockIdx.x * 256 + threadIdx.x;   // blockIdx.x 0..15
  int r0 = blockIdx.y * 64;                   // blockIdx.y 0..15
  float acc = 0.f;
#pragma unroll 8
  for (int r = 0; r < 64; r++) acc += hs[(size_t)(r0 + r) * HID + col];
  atomicAdd(hssum + col, acc);
}

// ============================================================
// K2: q2sum[i] = sum_k hssum[k] * Wq2[i,k]   (fp32, 1 wave/row)
// ============================================================
__global__ void k2_q2sum(const float* __restrict__ W,
                         const float* __restrict__ hssum,
                         float* __restrict__ q2sum) {
  int wave = threadIdx.x >> 6, lane = threadIdx.x & 63;
  int row = blockIdx.x * 4 + wave;
  const float4* wr = (const float4*)(W + (size_t)row * HID);
  const float4* xr = (const float4*)hssum;
  float acc = 0.f;
#pragma unroll
  for (int it = 0; it < 16; it++) {
    float4 a = wr[it * 64 + lane];
    float4 b = xr[it * 64 + lane];
    acc += a.x * b.x + a.y * b.y + a.z * b.z + a.w * b.w;
  }
#pragma unroll
  for (int off = 32; off > 0; off >>= 1) acc += __shfl_xor(acc, off, 64);
  if (lane == 0) q2sum[row] = acc;
}

// ============================================================
// K3: kb_scores[kb] = scale * dot(q2sum, kb_keys[kb, 0:4096])
// ============================================================
__global__ void k3_kbscore(const float* __restrict__ kbk,
                           const float* __restrict__ q2sum,
                           float* __restrict__ scores) {
  int wave = threadIdx.x >> 6, lane = threadIdx.x & 63;
  int row = blockIdx.x * 4 + wave;
  const float4* kr = (const float4*)(kbk + (size_t)row * 8192);  // slot 0 of 2
  const float4* xr = (const float4*)q2sum;
  float acc = 0.f;
#pragma unroll
  for (int it = 0; it < 16; it++) {
    float4 a = kr[it * 64 + lane];
    float4 b = xr[it * 64 + lane];
    acc += a.x * b.x + a.y * b.y + a.z * b.z + a.w * b.w;
  }
#pragma unroll
  for (int off = 32; off > 0; off >>= 1) acc += __shfl_xor(acc, off, 64);
  if (lane == 0) scores[row] = acc * SCALE;
}

// ============================================================
// K4: top-100 of 2048 scores, single wave, iterative argmax.
// ============================================================
__global__ void k4_topk(const float* __restrict__ scores, int* __restrict__ tidx) {
  int lane = threadIdx.x;  // blockDim = 64
  float v[32];
#pragma unroll
  for (int i = 0; i < 32; i++) v[i] = scores[i * 64 + lane];
  for (int t = 0; t < TOPK; t++) {
    float bm = -INFINITY; int bi = 0x7fffffff;
#pragma unroll
    for (int i = 0; i < 32; i++) {
      if (v[i] > bm) { bm = v[i]; bi = i * 64 + lane; }
    }
#pragma unroll
    for (int off = 32; off > 0; off >>= 1) {
      float ov = __shfl_xor(bm, off, 64);
      int   oi = __shfl_xor(bi, off, 64);
      if (ov > bm || (ov == bm && oi < bi)) { bm = ov; bi = oi; }
    }
    if (lane == 0) tidx[t] = bi;
    if ((bi & 63) == lane) {
      int slot = bi >> 6;
#pragma unroll
      for (int i = 0; i < 32; i++) if (i == slot) v[i] = -INFINITY;
    }
  }
}

// ============================================================
// K5: gather top-k KB rows (slot 0) -> bf16 [128][4096], zero-pad rows 100..127
// ============================================================
__global__ void k5_gather(const float* __restrict__ kbk, const float* __restrict__ kbv,
                          const int* __restrict__ tidx,
                          bf16_t* __restrict__ kbkt, bf16_t* __restrict__ kbvt) {
  int j = blockIdx.x;            // 0..127
  int tid = threadIdx.x;         // 256
  if (j < TOPK) {
    size_t src = (size_t)tidx[j] * 8192;
#pragma unroll
    for (int r = 0; r < 4; r++) {
      int i = (tid + r * 256) * 4;
      float4 a = *(const float4*)(kbk + src + i);
      float4 b = *(const float4*)(kbv + src + i);
      union { bf16_t h[4]; uint2 u; } pa, pb;
      pa.h[0] = __float2bfloat16(a.x); pa.h[1] = __float2bfloat16(a.y);
      pa.h[2] = __float2bfloat16(a.z); pa.h[3] = __float2bfloat16(a.w);
      pb.h[0] = __float2bfloat16(b.x); pb.h[1] = __float2bfloat16(b.y);
      pb.h[2] = __float2bfloat16(b.z); pb.h[3] = __float2bfloat16(b.w);
      *(uint2*)(kbkt + (size_t)j * HID + i) = pa.u;
      *(uint2*)(kbvt + (size_t)j * HID + i) = pb.u;
    }
  } else {
    uint2 z; z.x = 0u; z.y = 0u;
#pragma unroll
    for (int r = 0; r < 4; r++) {
      int i = (tid + r * 256) * 4;
      *(uint2*)(kbkt + (size_t)j * HID + i) = z;
      *(uint2*)(kbvt + (size_t)j * HID + i) = z;
    }
  }
}

// ============================================================
// gemm_proj: C = A[1024,4096] * B[16384,4096]^T, bf16, 256x256 tile,
// BK=32, 8 waves (2x4), ring-4 LDS (128 KiB), counted vmcnt, chunk-XOR
// swizzle, and REGISTER PREFETCH of next tile's fragments across the
// barrier (ping-pong frag sets). Boundary vmcnt(4) guarantees tile t+2
// resident, so body(t+1) may read tile t+2 fragments mid-body.
//   Ring safety: STAGE(t+3) overwrites buf[(t-1)&3]; last reads of that
//   buf (body(t-1) afB + body(t-2) prefetch) precede barrier(t-1) which
//   precedes this STAGE. vmcnt(4) is strictly stronger than round-1's
//   proven vmcnt(8), so no new write-before-read hazard.
// ============================================================
__global__ __launch_bounds__(512, 2) void gemm_proj(
    const bf16_t* __restrict__ A, const bf16_t* __restrict__ B,
    void* O0, void* O1, void* O2, void* O3) {
  __shared__ __attribute__((aligned(16))) bf16_t sm[4 * 16384];  // 128 KiB
  const int tid  = threadIdx.x;
  const int wave = tid >> 6, lane = tid & 63;
  const int lrow = lane & 15, quad = lane >> 4;
  const int wr = wave >> 2, wc = wave & 3;        // 2 x 4 wave grid
  const int bm = blockIdx.y * 256;
  const int bn = blockIdx.x * 256;
  const int srow = tid >> 2;                       // 0..127
  const int lc   = (tid & 3) ^ ((srow >> 1) & 3);  // pre-swizzled global chunk
  const int pc   = quad ^ ((lrow >> 1) & 3);       // swizzled read chunk

  const bf16_t* aS = A + (size_t)(bm + srow) * 4096 + lc * 8;
  const bf16_t* bS = B + (size_t)(bn + srow) * 4096 + lc * 8;
  bf16_t* const lw = sm + wave * 512;              // wave-uniform LDS base

  f32x4 acc[8][4];
  const f32x4 zero4 = {0.f, 0.f, 0.f, 0.f};
#pragma unroll
  for (int i = 0; i < 8; i++)
#pragma unroll
    for (int j = 0; j < 4; j++) acc[i][j] = zero4;

  auto STAGE = [&](int tt) {
    bf16_t* l = lw + (tt & 3) * 16384;
    const bf16_t* ga = aS + tt * 32;
    const bf16_t* gb = bS + tt * 32;
    __builtin_amdgcn_global_load_lds((gptr_t)ga,             (lptr_t)l,           16, 0, 0);
    __builtin_amdgcn_global_load_lds((gptr_t)(ga + 524288),  (lptr_t)(l + 4096),  16, 0, 0);
    __builtin_amdgcn_global_load_lds((gptr_t)gb,             (lptr_t)(l + 8192),  16, 0, 0);
    __builtin_amdgcn_global_load_lds((gptr_t)(gb + 524288),  (lptr_t)(l + 12288), 16, 0, 0);
  };

  short8 fa0[4], fb0[4], fa1[4], fb1[4], afB[4];

  // body: MFMA tile t from FAC/FBC (already in regs); read rows 64..127
  // of tile t (afB) and prefetch tile t+1 into FAN/FBN between clusters.
  auto body = [&](int t, short8 (&FAC)[4], short8 (&FBC)[4],
                  short8 (&FAN)[4], short8 (&FBN)[4],
                  bool pf, bool stg, int vmn, bool barr) {
    const bf16_t* Ab = sm + (t & 3) * 16384 + (wr * 128 + lrow) * 32 + pc * 8;
    if (stg) STAGE(t + 3);
#pragma unroll
    for (int i = 0; i < 4; i++) afB[i] = *(const short8*)(Ab + (i + 4) * 512);
    __builtin_amdgcn_s_setprio(1);
#pragma unroll
    for (int i = 0; i < 4; i++)
#pragma unroll
      for (int j = 0; j < 4; j++)
        acc[i][j] = __builtin_amdgcn_mfma_f32_16x16x32_bf16(FAC[i], FBC[j], acc[i][j], 0, 0, 0);
    __builtin_amdgcn_s_setprio(0);
    if (pf) {
      const bf16_t* An = sm + ((t + 1) & 3) * 16384 + (wr * 128 + lrow) * 32 + pc * 8;
      const bf16_t* Bn = sm + ((t + 1) & 3) * 16384 + 8192 + (wc * 64 + lrow) * 32 + pc * 8;
#pragma unroll
      for (int j = 0; j < 4; j++) FBN[j] = *(const short8*)(Bn + j * 512);
#pragma unroll
      for (int i = 0; i < 4; i++) FAN[i] = *(const short8*)(An + i * 512);
    }
    __builtin_amdgcn_s_setprio(1);
#pragma unroll
    for (int i = 0; i < 4; i++)
#pragma unroll
      for (int j = 0; j < 4; j++)
        acc[i + 4][j] = __builtin_amdgcn_mfma_f32_16x16x32_bf16(afB[i], FBC[j], acc[i + 4][j], 0, 0, 0);
    __builtin_amdgcn_s_setprio(0);
    if (vmn == 4) { VM4; }
    else if (vmn == 0) { VM0; }
    if (barr) __builtin_amdgcn_s_barrier();
  };

  // prologue: prime 3 tiles; vmcnt(4) -> tiles 0,1 resident; read tile 0 frags
  STAGE(0); STAGE(1); STAGE(2);
  VM4;
  __builtin_amdgcn_s_barrier();
  {
    const bf16_t* Ab = sm + (wr * 128 + lrow) * 32 + pc * 8;
    const bf16_t* Bb = sm + 8192 + (wc * 64 + lrow) * 32 + pc * 8;
#pragma unroll
    for (int j = 0; j < 4; j++) fb0[j] = *(const short8*)(Bb + j * 512);
#pragma unroll
    for (int i = 0; i < 4; i++) fa0[i] = *(const short8*)(Ab + i * 512);
  }

  // NT = 128 (K=4096, BK=32). bodies 0..123 paired, then tail 124..127.
  for (int t = 0; t < 124; t += 2) {
    body(t,     fa0, fb0, fa1, fb1, true, true, 4, true);
    body(t + 1, fa1, fb1, fa0, fb0, true, true, 4, true);
  }
  body(124, fa0, fb0, fa1, fb1, true,  true,  4, true);
  body(125, fa1, fb1, fa0, fb0, true,  false, 0, true);
  body(126, fa0, fb0, fa1, fb1, true,  false, -1, false);
  body(127, fa1, fb1, fa0, fb0, false, false, -1, false);

  bf16_t* dst = (bf16_t*)((bn >> 12) == 0 ? O0 : (bn >> 12) == 1 ? O1
                        : (bn >> 12) == 2 ? O2 : O3);
  const int nb = bn & 4095;
#pragma unroll
  for (int i = 0; i < 8; i++)
#pragma unroll
    for (int j = 0; j < 4; j++)
#pragma unroll
      for (int r = 0; r < 4; r++) {
        int m = bm + wr * 128 + i * 16 + quad * 4 + r;
        int n = nb + wc * 64 + j * 16 + lrow;
        dst[(size_t)m * 4096 + n] = __float2bfloat16(acc[i][j][r]);
      }
}

// ============================================================
// gemm_wo: out[1024,4096] = attnb[1024,4096] * Wob[4096,4096]^T, fp32 out.
// 128x128 tile, BK=64, 8 waves (2x4, per-wave 64x32), ring-4 LDS
// (4 x 32 KiB = 128 KiB), same counted-vmcnt + register-prefetch pipeline
// (4 loads/wave/stage -> identical vmcnt constants). No split-K, no
// atomics, no out-zeroing. grid (32,8) = 256 blocks.
// Swizzle: rows are 128 B (8 chunks); phys_chunk = logical ^ (row&7).
// ============================================================
__global__ __launch_bounds__(512, 2) void gemm_wo(
    const bf16_t* __restrict__ A, const bf16_t* __restrict__ B,
    float* __restrict__ out) {
  __shared__ __attribute__((aligned(16))) bf16_t sm[4 * 16384];  // 128 KiB
  const int tid  = threadIdx.x;
  const int wave = tid >> 6, lane = tid & 63;
  const int lrow = lane & 15, quad = lane >> 4;
  const int wrr = wave >> 2, wcc = wave & 3;      // 2 x 4 wave grid
  const int bm = blockIdx.y * 128;
  const int bn = blockIdx.x * 128;
  // staging: wave w<4 -> A rows [w*32,w*32+32); w>=4 -> B rows [(w-4)*32,..)
  const int srow8 = lane >> 3;                     // 0..7
  const int lcw   = (lane & 7) ^ srow8;            // pre-swizzled global chunk
  const int grp   = (wave & 3) * 32;
  const bf16_t* wS = ((wave < 4) ? A + (size_t)(bm + grp + srow8) * 4096
                                 : B + (size_t)(bn + grp + srow8) * 4096) + lcw * 8;
  bf16_t* const lw = sm + (wave < 4 ? 0 : 8192) + grp * 64;  // wave-uniform
  // swizzled read chunk offsets (elements) for kk=0,1
  const int pcw0 = ((quad)     ^ (lrow & 7)) * 8;
  const int pcw1 = ((4 + quad) ^ (lrow & 7)) * 8;

  f32x4 acc[4][2];
  const f32x4 zero4 = {0.f, 0.f, 0.f, 0.f};
#pragma unroll
  for (int i = 0; i < 4; i++)
#pragma unroll
    for (int j = 0; j < 2; j++) acc[i][j] = zero4;

  auto STAGE = [&](int tt) {
    bf16_t* l = lw + (tt & 3) * 16384;
    const bf16_t* g = wS + tt * 64;
    __builtin_amdgcn_global_load_lds((gptr_t)g,              (lptr_t)l,           16, 0, 0);
    __builtin_amdgcn_global_load_lds((gptr_t)(g + 32768),    (lptr_t)(l + 512),   16, 0, 0);
    __builtin_amdgcn_global_load_lds((gptr_t)(g + 65536),    (lptr_t)(l + 1024),  16, 0, 0);
    __builtin_amdgcn_global_load_lds((gptr_t)(g + 98304),    (lptr_t)(l + 1536),  16, 0, 0);
  };

  short8 ga0[8], gb0[4], ga1[8], gb1[4];

  auto rdfrag = [&](int t, short8 (&GA)[8], short8 (&GB)[4]) {
    const bf16_t* An = sm + (t & 3) * 16384;
    const bf16_t* Bn = An + 8192;
#pragma unroll
    for (int n = 0; n < 2; n++) {
      int row = wcc * 32 + n * 16 + lrow;
      GB[n * 2]     = *(const short8*)(Bn + row * 64 + pcw0);
      GB[n * 2 + 1] = *(const short8*)(Bn + row * 64 + pcw1);
    }
#pragma unroll
    for (int m = 0; m < 4; m++) {
      int row = wrr * 64 + m * 16 + lrow;
      GA[m * 2]     = *(const short8*)(An + row * 64 + pcw0);
      GA[m * 2 + 1] = *(const short8*)(An + row * 64 + pcw1);
    }
  };

  auto body = [&](int t, short8 (&GA)[8], short8 (&GB)[4],
                  short8 (&NA)[8], short8 (&NB)[4],
                  bool pf, bool stg, int vmn, bool barr) {
    if (stg) STAGE(t + 3);
    if (pf) rdfrag(t + 1, NA, NB);
    __builtin_amdgcn_s_setprio(1);
#pragma unroll
    for (int kk = 0; kk < 2; kk++)
#pragma unroll
      for (int m = 0; m < 4; m++)
#pragma unroll
        for (int n = 0; n < 2; n++)
          acc[m][n] = __builtin_amdgcn_mfma_f32_16x16x32_bf16(
              GA[m * 2 + kk], GB[n * 2 + kk], acc[m][n], 0, 0, 0);
    __builtin_amdgcn_s_setprio(0);
    if (vmn == 4) { VM4; }
    else if (vmn == 0) { VM0; }
    if (barr) __builtin_amdgcn_s_barrier();
  };

  STAGE(0); STAGE(1); STAGE(2);
  VM4;
  __builtin_amdgcn_s_barrier();
  rdfrag(0, ga0, gb0);

  // NT = 64 (K=4096, BK=64). bodies 0..59 paired, tail 60..63.
  for (int t = 0; t < 60; t += 2) {
    body(t,     ga0, gb0, ga1, gb1, true, true, 4, true);
    body(t + 1, ga1, gb1, ga0, gb0, true, true, 4, true);
  }
  body(60, ga0, gb0, ga1, gb1, true,  true,  4, true);
  body(61, ga1, gb1, ga0, gb0, true,  false, 0, true);
  body(62, ga0, gb0, ga1, gb1, true,  false, -1, false);
  body(63, ga1, gb1, ga0, gb0, false, false, -1, false);

#pragma unroll
  for (int m = 0; m < 4; m++)
#pragma unroll
    for (int n = 0; n < 2; n++)
#pragma unroll
      for (int r = 0; r < 4; r++) {
        int row = bm + wrr * 64 + m * 16 + quad * 4 + r;
        int col = bn + wcc * 32 + n * 16 + lrow;
        out[(size_t)row * 4096 + col] = acc[m][n][r];
      }
}

// ============================================================
// Fallback GEMM (round-1 structure) used when ws is too small for bf16 weights
// ============================================================
template<int OUT_BF16>
__global__ __launch_bounds__(256) void gemm_bt(
    const bf16_t* __restrict__ A,
    const float* __restrict__ B0, const float* __restrict__ B1,
    const float* __restrict__ B2, const float* __restrict__ B3,
    void* C0, void* C1, void* C2, void* C3) {
  const int z = blockIdx.z;
  const float* __restrict__ B = (z == 0) ? B0 : (z == 1) ? B1 : (z == 2) ? B2 : B3;
  void* Cv = (z == 0) ? C0 : (z == 1) ? C1 : (z == 2) ? C2 : C3;
  __shared__ bf16_t As[128][40];
  __shared__ bf16_t Bs[128][40];
  const int tid = threadIdx.x;
  const int bm = blockIdx.y * 128, bn = blockIdx.x * 128;
  const int wave = tid >> 6, lane = tid & 63;
  const int wr = wave >> 1, wc = wave & 1;
  const int lrow = lane & 15, quad = lane >> 4;
  f32x4 acc[4][4];
  const f32x4 zero4 = {0.f, 0.f, 0.f, 0.f};
#pragma unroll
  for (int i = 0; i < 4; i++)
#pragma unroll
    for (int j = 0; j < 4; j++) acc[i][j] = zero4;
  const int arow = tid >> 2, ach = tid & 3;
  const int brow = tid >> 3, bch = tid & 7;
  for (int k0 = 0; k0 < 4096; k0 += 32) {
    __syncthreads();
#pragma unroll
    for (int r = 0; r < 2; r++) {
      int row = arow + r * 64;
      uint4 val = *(const uint4*)(A + (size_t)(bm + row) * 4096 + k0 + ach * 8);
      *(uint4*)(&As[row][ach * 8]) = val;
    }
#pragma unroll
    for (int r = 0; r < 4; r++) {
      int row = brow + r * 32;
      float4 f = *(const float4*)(B + (size_t)(bn + row) * 4096 + k0 + bch * 4);
      union { bf16_t h[4]; uint2 u; } p;
      p.h[0] = __float2bfloat16(f.x); p.h[1] = __float2bfloat16(f.y);
      p.h[2] = __float2bfloat16(f.z); p.h[3] = __float2bfloat16(f.w);
      *(uint2*)(&Bs[row][bch * 4]) = p.u;
    }
    __syncthreads();
    short8 af[4], bfr[4];
#pragma unroll
    for (int i = 0; i < 4; i++)
      af[i] = *(const short8*)(&As[wr * 64 + i * 16 + lrow][quad * 8]);
#pragma unroll
    for (int j = 0; j < 4; j++)
      bfr[j] = *(const short8*)(&Bs[wc * 64 + j * 16 + lrow][quad * 8]);
#pragma unroll
    for (int i = 0; i < 4; i++)
#pragma unroll
      for (int j = 0; j < 4; j++)
        acc[i][j] = __builtin_amdgcn_mfma_f32_16x16x32_bf16(af[i], bfr[j], acc[i][j], 0, 0, 0);
  }
#pragma unroll
  for (int i = 0; i < 4; i++)
#pragma unroll
    for (int j = 0; j < 4; j++)
#pragma unroll
      for (int r = 0; r < 4; r++) {
        int m = bm + wr * 64 + i * 16 + quad * 4 + r;
        int n = bn + wc * 64 + j * 16 + lrow;
        if (OUT_BF16)
          ((bf16_t*)Cv)[(size_t)m * 4096 + n] = __float2bfloat16(acc[i][j][r]);
        else
          ((float*)Cv)[(size_t)m * 4096 + n] = acc[i][j][r];
      }
}

// ============================================================
// K7: RoPE on q and k (bf16 in-place). pair (d, d+64), d<64.
// ============================================================
__global__ void k7_rope(bf16_t* __restrict__ q, bf16_t* __restrict__ k,
                        const int* __restrict__ pos_ids) {
  int t = blockIdx.x * 256 + threadIdx.x;
  int d = t & 63;
  int h = (t >> 6) & 31;
  int s = t >> 11;
  float pos = (float)pos_ids[s];
  float inv = exp2f(-(float)d * 0.20762050593046f);
  float ang = pos * inv;
  float c = cosf(ang), si = sinf(ang);
  size_t i1 = (size_t)s * HID + h * HD + d;
  size_t i2 = i1 + 64;
  float a1 = __bfloat162float(q[i1]), a2 = __bfloat162float(q[i2]);
  q[i1] = __float2bfloat16(a1 * c - a2 * si);
  q[i2] = __float2bfloat16(a2 * c + a1 * si);
  float b1 = __bfloat162float(k[i1]), b2 = __bfloat162float(k[i2]);
  k[i1] = __float2bfloat16(b1 * c - b2 * si);
  k[i2] = __float2bfloat16(b2 * c + b1 * si);
}

// ============================================================
// K8: flash attention (unchanged)
// ============================================================
#define FA_PAD 136
__global__ __launch_bounds__(256) void k8_flash(
    const bf16_t* __restrict__ qg, const bf16_t* __restrict__ q2g,
    const bf16_t* __restrict__ kg, const bf16_t* __restrict__ vg,
    const bf16_t* __restrict__ kbkt, const bf16_t* __restrict__ kbvt,
    const float* __restrict__ shift_p,
    bf16_t* __restrict__ outb) {
  __shared__ bf16_t KV[128][FA_PAD];
  __shared__ bf16_t Ps[4][16][FA_PAD];
  int qt = 15 - (int)blockIdx.x;
  int h = blockIdx.y;
  int q0 = qt * 64;
  int tid = threadIdx.x;
  int wave = tid >> 6, lane = tid & 63;
  int lrow = lane & 15, quad = lane >> 4;

  short8 qf[4], q2f[4];
  {
    const size_t base = (size_t)(q0 + wave * 16 + lrow) * HID + h * HD;
#pragma unroll
    for (int kc = 0; kc < 4; kc++) {
      qf[kc]  = *(const short8*)(qg  + base + kc * 32 + quad * 8);
      q2f[kc] = *(const short8*)(q2g + base + kc * 32 + quad * 8);
    }
  }
  const f32x4 zero4 = {0.f, 0.f, 0.f, 0.f};
  f32x4 O[8];
#pragma unroll
  for (int df = 0; df < 8; df++) O[df] = zero4;
  float m_i[4], l_i[4];
#pragma unroll
  for (int r = 0; r < 4; r++) { m_i[r] = -INFINITY; l_i[r] = 0.f; }
  float shift = shift_p[h];

  int nt = (q0 + 63) / 128 + 1;
  for (int tile = -1; tile < nt; tile++) {
    const bf16_t* ksrc = (tile < 0) ? (kbkt + h * HD)
                                    : (kg + (size_t)tile * 128 * HID + h * HD);
    const bf16_t* vsrc = (tile < 0) ? (kbvt + h * HD)
                                    : (vg + (size_t)tile * 128 * HID + h * HD);
    __syncthreads();
    {
      int rbase = tid >> 4, ch = tid & 15;
#pragma unroll
      for (int rr = 0; rr < 8; rr++) {
        int row = rr * 16 + rbase;
        uint4 val = *(const uint4*)(ksrc + (size_t)row * HID + ch * 8);
        *(uint4*)(&KV[row][ch * 8]) = val;
      }
    }
    __syncthreads();
    f32x4 Sv[8];
#pragma unroll
    for (int jf = 0; jf < 8; jf++) {
      short8 kf[4];
#pragma unroll
      for (int kc = 0; kc < 4; kc++)
        kf[kc] = *(const short8*)(&KV[jf * 16 + lrow][kc * 32 + quad * 8]);
      f32x4 s = zero4;
      if (tile < 0) {
#pragma unroll
        for (int kc = 0; kc < 4; kc++)
          s = __builtin_amdgcn_mfma_f32_16x16x32_bf16(q2f[kc], kf[kc], s, 0, 0, 0);
      } else {
#pragma unroll
        for (int kc = 0; kc < 4; kc++)
          s = __builtin_amdgcn_mfma_f32_16x16x32_bf16(qf[kc], kf[kc], s, 0, 0, 0);
      }
      Sv[jf] = s;
    }
#pragma unroll
    for (int jf = 0; jf < 8; jf++)
#pragma unroll
      for (int r = 0; r < 4; r++) {
        float val = Sv[jf][r] * SCALE;
        if (tile < 0) {
          val += shift;
          int col = jf * 16 + lrow;
          if (col >= TOPK) val = -1e30f;
        } else {
          int srow = q0 + wave * 16 + quad * 4 + r;
          int tcol = tile * 128 + jf * 16 + lrow;
          if (tcol > srow) val -= 1e9f;
        }
        Sv[jf][r] = val;
      }
    float alpha[4];
#pragma unroll
    for (int r = 0; r < 4; r++) {
      float tm = Sv[0][r];
#pragma unroll
      for (int jf = 1; jf < 8; jf++) tm = fmaxf(tm, Sv[jf][r]);
#pragma unroll
      for (int off = 1; off < 16; off <<= 1) tm = fmaxf(tm, __shfl_xor(tm, off, 64));
      float mn = fmaxf(m_i[r], tm);
      alpha[r] = __expf(m_i[r] - mn);
      m_i[r] = mn;
    }
    float rsum[4] = {0.f, 0.f, 0.f, 0.f};
#pragma unroll
    for (int jf = 0; jf < 8; jf++)
#pragma unroll
      for (int r = 0; r < 4; r++) {
        float p = __expf(Sv[jf][r] - m_i[r]);
        Sv[jf][r] = p;
        rsum[r] += p;
      }
#pragma unroll
    for (int r = 0; r < 4; r++) {
#pragma unroll
      for (int off = 1; off < 16; off <<= 1) rsum[r] += __shfl_xor(rsum[r], off, 64);
      l_i[r] = l_i[r] * alpha[r] + rsum[r];
    }
#pragma unroll
    for (int jf = 0; jf < 8; jf++)
#pragma unroll
      for (int r = 0; r < 4; r++)
        Ps[wave][quad * 4 + r][jf * 16 + lrow] = __float2bfloat16(Sv[jf][r]);
#pragma unroll
    for (int df = 0; df < 8; df++)
#pragma unroll
      for (int r = 0; r < 4; r++) O[df][r] *= alpha[r];
    __syncthreads();
    {
      int rbase = tid >> 4, ch = tid & 15;
#pragma unroll
      for (int rr = 0; rr < 8; rr++) {
        int t = rr * 16 + rbase;
        union { uint4 u; bf16_t hx[8]; } vv;
        vv.u = *(const uint4*)(vsrc + (size_t)t * HID + ch * 8);
        int cs = ((t >> 3) ^ ch) & 15;
        int tl = t & 7;
#pragma unroll
        for (int e = 0; e < 8; e++)
          KV[ch * 8 + e][cs * 8 + tl] = vv.hx[e];
      }
    }
    __syncthreads();
    short8 pf[4];
#pragma unroll
    for (int kc = 0; kc < 4; kc++)
      pf[kc] = *(const short8*)(&Ps[wave][lrow][kc * 32 + quad * 8]);
#pragma unroll
    for (int df = 0; df < 8; df++) {
      int d = df * 16 + lrow;
      int sw = (d >> 3) & 15;
#pragma unroll
      for (int kc = 0; kc < 4; kc++) {
        short8 vf = *(const short8*)(&KV[d][(((kc * 4 + quad) ^ sw) & 15) * 8]);
        O[df] = __builtin_amdgcn_mfma_f32_16x16x32_bf16(pf[kc], vf, O[df], 0, 0, 0);
      }
    }
  }
#pragma unroll
  for (int df = 0; df < 8; df++)
#pragma unroll
    for (int r = 0; r < 4; r++) {
      int srow = q0 + wave * 16 + quad * 4 + r;
      float val = O[df][r] / l_i[r];
      outb[(size_t)srow * HID + h * HD + df * 16 + lrow] = __float2bfloat16(val);
    }
}

// ============================================================
extern "C" void kernel_launch(void* const* d_in, const int* in_sizes, int n_in,
                              void* d_out, int out_size, void* d_ws, size_t ws_size,
                              hipStream_t stream) {
  const float* hs    = (const float*)d_in[0];
  const int*   pos   = (const int*)d_in[2];
  const float* kbk   = (const float*)d_in[3];
  const float* kbv   = (const float*)d_in[4];
  const float* Wq    = (const float*)d_in[5];
  const float* Wq2   = (const float*)d_in[6];
  const float* Wk    = (const float*)d_in[7];
  const float* Wv    = (const float*)d_in[8];
  const float* Wo    = (const float*)d_in[9];
  const float* shift = (const float*)d_in[10];
  float* out = (float*)d_out;

  char* ws = (char*)d_ws;
  const size_t MB8 = 8388608;
  bf16_t* qb    = (bf16_t*)(ws);
  bf16_t* q2b   = (bf16_t*)(ws + MB8);
  bf16_t* kbuf  = (bf16_t*)(ws + 2 * MB8);
  bf16_t* vbuf  = (bf16_t*)(ws + 3 * MB8);
  bf16_t* hsb   = (bf16_t*)(ws + 4 * MB8);   // reused as attn output
  bf16_t* kbkt  = (bf16_t*)(ws + 5 * MB8);
  bf16_t* kbvt  = (bf16_t*)(ws + 5 * MB8 + 1048576);
  float*  hssum = (float*)(ws + 5 * MB8 + 2 * 1048576);
  float*  q2s   = (float*)(ws + 5 * MB8 + 2 * 1048576 + 16384);
  float*  scr   = (float*)(ws + 5 * MB8 + 2 * 1048576 + 32768);
  int*    tidx  = (int*)(ws + 5 * MB8 + 2 * 1048576 + 40960);
  bf16_t* attnb = hsb;
  // bf16 weight staging
  const size_t WCAT_OFF = 48ull * 1048576;
  bf16_t* Wcat = (bf16_t*)(ws + WCAT_OFF);                 // 128 MB
  bf16_t* Wob  = (bf16_t*)(ws + WCAT_OFF + 134217728);     // 32 MB
  const size_t WS_NEED = WCAT_OFF + 134217728 + 33554432;
  const bool big_ws = (ws_size >= WS_NEED);

  k0_zero<<<dim3(1), dim3(256), 0, stream>>>(hssum);
  if (big_ws)
    kw_conv<<<dim3(16384, 5), dim3(256), 0, stream>>>(Wq, Wq2, Wk, Wv, Wo, Wcat, Wob);
  k1_convert<<<dim3(4096), dim3(256), 0, stream>>>(hs, hsb);
  k1_colsum<<<dim3(16, 16), dim3(256), 0, stream>>>(hs, hssum);
  k2_q2sum<<<dim3(1024), dim3(256), 0, stream>>>(Wq2, hssum, q2s);
  k3_kbscore<<<dim3(512), dim3(256), 0, stream>>>(kbk, q2s, scr);
  k4_topk<<<dim3(1), dim3(64), 0, stream>>>(scr, tidx);
  k5_gather<<<dim3(128), dim3(256), 0, stream>>>(kbk, kbv, tidx, kbkt, kbvt);

  if (big_ws) {
    // 256x256 tiles: grid 64x4 = 256 blocks = 1 per CU
    gemm_proj<<<dim3(64, 4), dim3(512), 0, stream>>>(
        hsb, Wcat, (void*)qb, (void*)q2b, (void*)kbuf, (void*)vbuf);
  } else {
    gemm_bt<1><<<dim3(32, 8, 4), dim3(256), 0, stream>>>(
        hsb, Wq, Wq2, Wk, Wv, (void*)qb, (void*)q2b, (void*)kbuf, (void*)vbuf);
  }
  k7_rope<<<dim3(8192), dim3(256), 0, stream>>>(qb, kbuf, pos);
  k8_flash<<<dim3(16, 32), dim3(256), 0, stream>>>(
      qb, q2b, kbuf, vbuf, kbkt, kbvt, shift, attnb);
  if (big_ws) {
    // 128x128 tiles, full K, no atomics: grid 32x8 = 256 blocks
    gemm_wo<<<dim3(32, 8), dim3(512), 0, stream>>>(attnb, Wob, out);
  } else {
    gemm_bt<0><<<dim3(32, 8, 1), dim3(256), 0, stream>>>(
        attnb, Wo, Wo, Wo, Wo, (void*)out, (void*)out, (void*)out, (void*)out);
  }
}